// Round 6
// baseline (238.212 us; speedup 1.0000x reference)
//
#include <hip/hip_runtime.h>
#include <hip/hip_bf16.h>

#define Bb 64
#define Ll 200
#define NSs 1000
#define Dd 128
#define Mm 50

__device__ __forceinline__ float bcast_lane(float v, int l) {
    return __int_as_float(__builtin_amdgcn_readlane(__float_as_int(v), l));
}

// ============ fused kernel 1+2: w = softmax(k@Mk^T); e,a = gates(v) ============
// 32 pos/block, 256 thr = 4 waves. Phase 1: stage Mk + 32 k-rows, each wave
// computes softmax for 8 positions. Phase 2 (LDS reused): v-tile (pre-gathered
// into registers during phase 1) + wave-private weight tiles, 4x4 register tile.
__global__ void __launch_bounds__(256) kern_wea(
        const int* __restrict__ skills,
        const int* __restrict__ responses,
        const float* __restrict__ k_emb,
        const float* __restrict__ v_emb,
        const float* __restrict__ Mk,
        const float* __restrict__ e_W, const float* __restrict__ e_b,
        const float* __restrict__ a_W, const float* __restrict__ a_b,
        float* __restrict__ w_out,
        float* __restrict__ e_out, float* __restrict__ a_out) {
    __shared__ float smem[21120];                       // 84.5 KB
    float (*mk)[Dd + 4] = (float(*)[Dd + 4])smem;             // phase1: 50 rows
    float (*kr)[Dd + 4] = (float(*)[Dd + 4])(smem + 6600);    // phase1: 32 rows
    float (*vt)[Dd + 4] = (float(*)[Dd + 4])smem;             // phase2: 32 rows
    float (*wt)[Dd + 4] = (float(*)[Dd + 4])(smem + 4224);    // phase2: 4x32 rows

    int tid  = threadIdx.x;
    int blk  = blockIdx.x;
    int wave = tid >> 6, lane = tid & 63;

    // issue v-gather into registers (consumed after phase 1)
    float4 vpre[4];
    int    vr[4];
#pragma unroll
    for (int i = 0; i < 4; ++i) {
        int lin = i * 256 + tid;
        int r   = lin >> 5;
        int c4  = lin & 31;
        int bl  = blk * 32 + r;
        int rr  = responses[bl];
        int x   = skills[bl] + NSs * ((rr > -1) ? rr : 0);
        vpre[i] = ((const float4*)(v_emb + (size_t)x * Dd))[c4];
        vr[i]   = r; (void)vr;
    }

    // stage Mk (1600 float4) and 32 k rows (1024 float4)
    for (int lin = tid; lin < (Mm * Dd) / 4; lin += 256) {
        float4 f = ((const float4*)Mk)[lin];
        *(float4*)&mk[lin >> 5][(lin & 31) * 4] = f;
    }
#pragma unroll
    for (int i = 0; i < 4; ++i) {
        int lin = i * 256 + tid;
        int r   = lin >> 5;
        int c4  = lin & 31;
        float4 f = ((const float4*)(k_emb + (size_t)skills[blk * 32 + r] * Dd))[c4];
        *(float4*)&kr[r][c4 * 4] = f;
    }
    __syncthreads();

    // ---- phase 1: w for 8 positions per wave ----
    int mrow = (lane < Mm) ? lane : 0;
    float acc8[8] = {};
#pragma unroll 2
    for (int q = 0; q < 32; ++q) {
        float4 mkv = *(const float4*)&mk[mrow][q * 4];
#pragma unroll
        for (int i = 0; i < 8; ++i) {
            float4 kv = *(const float4*)&kr[wave * 8 + i][q * 4];
            acc8[i] = fmaf(mkv.x, kv.x, acc8[i]);
            acc8[i] = fmaf(mkv.y, kv.y, acc8[i]);
            acc8[i] = fmaf(mkv.z, kv.z, acc8[i]);
            acc8[i] = fmaf(mkv.w, kv.w, acc8[i]);
        }
    }
#pragma unroll
    for (int i = 0; i < 8; ++i) {
        float logit = (lane < Mm) ? acc8[i] : -1e30f;
        float mx = logit;
        for (int off = 32; off > 0; off >>= 1) mx = fmaxf(mx, __shfl_down(mx, off));
        mx = __shfl(mx, 0);
        float ex = (lane < Mm) ? expf(logit - mx) : 0.f;
        float sm = ex;
        for (int off = 32; off > 0; off >>= 1) sm += __shfl_down(sm, off);
        sm = __shfl(sm, 0);
        int bl = blk * 32 + wave * 8 + i;
        if (lane < Mm) w_out[(size_t)bl * Mm + lane] = ex / sm;
    }
    __syncthreads();   // done reading mk/kr — LDS region is reused below

    // ---- phase 2: e/a GEMM ----
#pragma unroll
    for (int i = 0; i < 4; ++i) {
        int lin = i * 256 + tid;
        *(float4*)&vt[lin >> 5][(lin & 31) * 4] = vpre[i];
    }

    int pg = lane >> 3, og = lane & 7;
    int p0 = pg * 4, o0 = og * 4;

    for (int s = 0; s < 2; ++s) {
        int base_row = wave * 64 + s * 32;
        bool is_e    = base_row < 128;
        const float* W = is_e ? e_W : a_W;
        int wrow0 = is_e ? base_row : base_row - 128;

#pragma unroll
        for (int i = 0; i < 16; ++i) {
            int lin = i * 64 + lane;
            int r   = lin >> 5;
            int c4  = lin & 31;
            float4 f = ((const float4*)(W + (size_t)(wrow0 + r) * Dd))[c4];
            *(float4*)&wt[wave * 32 + r][c4 * 4] = f;
        }
        __syncthreads();   // also publishes vt on s==0

        float acc[4][4] = {};
#pragma unroll 2
        for (int q = 0; q < 32; ++q) {
            float4 av[4], bv[4];
#pragma unroll
            for (int i = 0; i < 4; ++i) av[i] = *(const float4*)&vt[p0 + i][q * 4];
#pragma unroll
            for (int j = 0; j < 4; ++j) bv[j] = *(const float4*)&wt[wave * 32 + o0 + j][q * 4];
#pragma unroll
            for (int i = 0; i < 4; ++i)
#pragma unroll
                for (int j = 0; j < 4; ++j) {
                    acc[i][j] = fmaf(av[i].x, bv[j].x, acc[i][j]);
                    acc[i][j] = fmaf(av[i].y, bv[j].y, acc[i][j]);
                    acc[i][j] = fmaf(av[i].z, bv[j].z, acc[i][j]);
                    acc[i][j] = fmaf(av[i].w, bv[j].w, acc[i][j]);
                }
        }

        int rowm0 = wrow0 + o0;
        float4 bias = *(const float4*)((is_e ? e_b : a_b) + rowm0);
        float* dst  = is_e ? e_out : a_out;
#pragma unroll
        for (int i = 0; i < 4; ++i) {
            int bl = blk * 32 + p0 + i;
            float4 r;
            if (is_e) {
                r.x = 1.f / (1.f + expf(-(acc[i][0] + bias.x)));
                r.y = 1.f / (1.f + expf(-(acc[i][1] + bias.y)));
                r.z = 1.f / (1.f + expf(-(acc[i][2] + bias.z)));
                r.w = 1.f / (1.f + expf(-(acc[i][3] + bias.w)));
            } else {
                r.x = tanhf(acc[i][0] + bias.x);
                r.y = tanhf(acc[i][1] + bias.y);
                r.z = tanhf(acc[i][2] + bias.z);
                r.w = tanhf(acc[i][3] + bias.w);
            }
            *(float4*)&dst[(size_t)bl * Dd + rowm0] = r;
        }
        __syncthreads();
    }
}

// ============ scan pass 1: per-chunk affine transfer (P, Q) ============
// Depth-3 rotating prefetch: load step t+2 while computing step t.
#define PQ_LOAD(S, tt) do { int _t = (tt);                                   \
    if (_t < T) { size_t _bl = blBase + _t;                                  \
        w##S = (lane < Mm) ? w_ws[_bl * Mm + lane] : 0.f;                    \
        e##S = e_ws[_bl * Dd + d];  a##S = a_ws[_bl * Dd + d]; } } while (0)

#define PQ_BODY(S) do {                                                      \
    _Pragma("unroll")                                                        \
    for (int m = 0; m < Mm; ++m) {                                           \
        float wm = bcast_lane(w##S, m);                                      \
        float A  = fmaf(-wm, e##S, 1.f);                                     \
        Q[m] = fmaf(A, Q[m], wm * a##S);                                     \
        P[m] *= A; } } while (0)

__global__ void __launch_bounds__(128) kern_scan_pq(
        const float* __restrict__ w_ws,
        const float* __restrict__ e_ws,
        const float* __restrict__ a_ws,
        float* __restrict__ P_ws, float* __restrict__ Q_ws,
        int C, int T) {
    int b = blockIdx.x / C, c = blockIdx.x % C;
    int d = threadIdx.x;
    int lane = d & 63;
    float P[Mm], Q[Mm];
#pragma unroll
    for (int m = 0; m < Mm; ++m) { P[m] = 1.f; Q[m] = 0.f; }

    size_t blBase = (size_t)b * Ll + (size_t)c * T;
    float w0 = 0.f, e0 = 0.f, a0 = 0.f;
    float w1 = 0.f, e1 = 0.f, a1 = 0.f;
    float w2 = 0.f, e2 = 0.f, a2 = 0.f;
    PQ_LOAD(0, 0);
    PQ_LOAD(1, 1);
    for (int tt = 0; tt < T; tt += 3) {
        PQ_LOAD(2, tt + 2);  PQ_BODY(0);
        if (tt + 1 < T) { PQ_LOAD(0, tt + 3);  PQ_BODY(1); }
        if (tt + 2 < T) { PQ_LOAD(1, tt + 4);  PQ_BODY(2); }
    }
    size_t base = ((size_t)(b * C + c)) * (Mm * Dd) + d;
#pragma unroll
    for (int m = 0; m < Mm; ++m) {
        P_ws[base + m * Dd] = P[m];
        Q_ws[base + m * Dd] = Q[m];
    }
}

// ============ scan pass 2: chunk-boundary combine (compile-time C) ============
template <int CC>
__global__ void kern_scan_comb_t(
        const float* __restrict__ Mv0,
        const float* __restrict__ P_ws, const float* __restrict__ Q_ws,
        float* __restrict__ S_ws) {
    int idx = blockIdx.x * 256 + threadIdx.x;
    int b   = idx / (Mm * Dd);
    int md  = idx % (Mm * Dd);
    float Pr[CC - 1], Qr[CC - 1];
#pragma unroll
    for (int c = 0; c < CC - 1; ++c) {          // all loads issued together
        size_t pq = ((size_t)(b * CC + c)) * (Mm * Dd) + md;
        Pr[c] = P_ws[pq];
        Qr[c] = Q_ws[pq];
    }
    float s = Mv0[md];
#pragma unroll
    for (int c = 0; c < CC - 1; ++c) {
        s = fmaf(Pr[c], s, Qr[c]);
        S_ws[((size_t)(b * (CC - 1) + c)) * (Mm * Dd) + md] = s;
    }
}

// ============ scan pass 3: rescan chunk from known start, emit read ============
#define RD_BODY(S, tt) do {                                                  \
    float acc0 = 0.f, acc1 = 0.f, acc2 = 0.f, acc3 = 0.f;                    \
    _Pragma("unroll")                                                        \
    for (int m = 0; m < Mm; m += 2) {                                        \
        float wm0 = bcast_lane(w##S, m);                                     \
        float wm1 = bcast_lane(w##S, m + 1);                                 \
        acc0 = fmaf(wm0, mv[m], acc0);                                       \
        mv[m] = fmaf(wm0, fmaf(-e##S, mv[m], a##S), mv[m]);                  \
        acc1 = fmaf(wm1, mv[m + 1], acc1);                                   \
        mv[m + 1] = fmaf(wm1, fmaf(-e##S, mv[m + 1], a##S), mv[m + 1]);      \
    }                                                                        \
    read_ws[(blBase + (tt)) * Dd + d] = (acc0 + acc1) + (acc2 + acc3);       \
    } while (0)

__global__ void __launch_bounds__(128) kern_scan_rd(
        const float* __restrict__ Mv0,
        const float* __restrict__ S_ws,
        const float* __restrict__ w_ws,
        const float* __restrict__ e_ws,
        const float* __restrict__ a_ws,
        float* __restrict__ read_ws,
        int C, int T) {
    int b = blockIdx.x / C, c = blockIdx.x % C;
    int d = threadIdx.x;
    int lane = d & 63;
    float mv[Mm];
    if (c == 0) {
#pragma unroll
        for (int m = 0; m < Mm; ++m) mv[m] = Mv0[m * Dd + d];
    } else {
        size_t sb = ((size_t)(b * (C - 1) + (c - 1))) * (Mm * Dd) + d;
#pragma unroll
        for (int m = 0; m < Mm; ++m) mv[m] = S_ws[sb + m * Dd];
    }

    size_t blBase = (size_t)b * Ll + (size_t)c * T;
    float w0 = 0.f, e0 = 0.f, a0 = 0.f;
    float w1 = 0.f, e1 = 0.f, a1 = 0.f;
    float w2 = 0.f, e2 = 0.f, a2 = 0.f;
    PQ_LOAD(0, 0);
    PQ_LOAD(1, 1);
    for (int tt = 0; tt < T; tt += 3) {
        PQ_LOAD(2, tt + 2);  RD_BODY(0, tt);
        if (tt + 1 < T) { PQ_LOAD(0, tt + 3);  RD_BODY(1, tt + 1); }
        if (tt + 2 < T) { PQ_LOAD(1, tt + 4);  RD_BODY(2, tt + 2); }
    }
}

// ============ kernel 4: p = sigmoid(tanh([read|k]@fW^T+fb) @ pW^T + pb) ============
__global__ void __launch_bounds__(256) kern_out(
        const int* __restrict__ skills,
        const float* __restrict__ read_ws,
        const float* __restrict__ k_emb,
        const float* __restrict__ f_W, const float* __restrict__ f_b,
        const float* __restrict__ p_W, const float* __restrict__ p_b,
        float* __restrict__ out) {
    __shared__ float ct[32][2 * Dd + 8];
    __shared__ float wt[4][32][Dd + 4];
    __shared__ float pf[32][8];
    int tid = threadIdx.x;
    int blk = blockIdx.x;

#pragma unroll
    for (int i = 0; i < 8; ++i) {
        int lin = i * 256 + tid;
        int r   = lin >> 6;
        int c4  = lin & 63;
        int idx = blk * 32 + r;
        int b   = idx / (Ll - 1);
        int l   = idx % (Ll - 1) + 1;
        int bl  = b * Ll + l;
        float4 f;
        if (c4 < 32) f = ((const float4*)(read_ws + (size_t)bl * Dd))[c4];
        else         f = ((const float4*)(k_emb + (size_t)skills[bl] * Dd))[c4 - 32];
        *(float4*)&ct[r][c4 * 4] = f;
    }
    ((float*)pf)[tid] = 0.f;
    __syncthreads();

    int wave = tid >> 6, lane = tid & 63;
    int pg = lane >> 3, og = lane & 7;
    int p0 = pg * 4, o0 = og * 4;

    float acc[4][4] = {};
    for (int h = 0; h < 2; ++h) {
#pragma unroll
        for (int i = 0; i < 16; ++i) {
            int lin = i * 64 + lane;
            int r   = lin >> 5;
            int c4  = lin & 31;
            float4 f = ((const float4*)(f_W + (size_t)(wave * 32 + r) * (2 * Dd)))[h * 32 + c4];
            *(float4*)&wt[wave][r][c4 * 4] = f;
        }
        __syncthreads();
#pragma unroll 2
        for (int q = 0; q < 32; ++q) {
            int k = h * 128 + q * 4;
            float4 av[4], bv[4];
#pragma unroll
            for (int i = 0; i < 4; ++i) av[i] = *(const float4*)&ct[p0 + i][k];
#pragma unroll
            for (int j = 0; j < 4; ++j) bv[j] = *(const float4*)&wt[wave][o0 + j][q * 4];
#pragma unroll
            for (int i = 0; i < 4; ++i)
#pragma unroll
                for (int j = 0; j < 4; ++j) {
                    acc[i][j] = fmaf(av[i].x, bv[j].x, acc[i][j]);
                    acc[i][j] = fmaf(av[i].y, bv[j].y, acc[i][j]);
                    acc[i][j] = fmaf(av[i].z, bv[j].z, acc[i][j]);
                    acc[i][j] = fmaf(av[i].w, bv[j].w, acc[i][j]);
                }
        }
        __syncthreads();
    }

    int row0 = wave * 32 + o0;
    float4 fb = *(const float4*)&f_b[row0];
    float4 pw = *(const float4*)&p_W[row0];
#pragma unroll
    for (int i = 0; i < 4; ++i) {
        float pp = 0.f;
        pp = fmaf(tanhf(acc[i][0] + fb.x), pw.x, pp);
        pp = fmaf(tanhf(acc[i][1] + fb.y), pw.y, pp);
        pp = fmaf(tanhf(acc[i][2] + fb.z), pw.z, pp);
        pp = fmaf(tanhf(acc[i][3] + fb.w), pw.w, pp);
        for (int off = 4; off > 0; off >>= 1) pp += __shfl_down(pp, off, 8);
        if (og == 0) pf[p0 + i][wave] = pp;
    }
    __syncthreads();
    if (tid < 32) {
        float s = pf[tid][0] + pf[tid][1] + pf[tid][2] + pf[tid][3] + p_b[0];
        out[blk * 32 + tid] = 1.f / (1.f + expf(-s));
    }
}

extern "C" void kernel_launch(void* const* d_in, const int* in_sizes, int n_in,
                              void* d_out, int out_size, void* d_ws, size_t ws_size,
                              hipStream_t stream) {
    const int*   skills    = (const int*)  d_in[0];
    const int*   responses = (const int*)  d_in[1];
    const float* k_emb     = (const float*)d_in[2];
    const float* v_emb     = (const float*)d_in[3];
    const float* Mk        = (const float*)d_in[4];
    const float* Mv0       = (const float*)d_in[5];
    const float* e_W       = (const float*)d_in[6];
    const float* e_b       = (const float*)d_in[7];
    const float* a_W       = (const float*)d_in[8];
    const float* a_b       = (const float*)d_in[9];
    const float* f_W       = (const float*)d_in[10];
    const float* f_b       = (const float*)d_in[11];
    const float* p_W       = (const float*)d_in[12];
    const float* p_b       = (const float*)d_in[13];
    (void)in_sizes; (void)n_in; (void)out_size;

    float* out = (float*)d_out;

    float* ws      = (float*)d_ws;
    float* w_ws    = ws;                                  // B*L*M
    float* e_ws    = w_ws + (size_t)Bb * Ll * Mm;         // B*L*D
    float* a_ws    = e_ws + (size_t)Bb * Ll * Dd;         // B*L*D
    float* read_ws = a_ws + (size_t)Bb * Ll * Dd;         // B*L*D
    float* extra   = read_ws + (size_t)Bb * Ll * Dd;

    const size_t baseF = (size_t)Bb * Ll * Mm + 3 * (size_t)Bb * Ll * Dd;
    const size_t BMD   = (size_t)Bb * Mm * Dd;
    int C = 1;
    const int cands[3] = {8, 5, 2};
    for (int i = 0; i < 3; ++i) {
        size_t need = (baseF + BMD * (3 * (size_t)cands[i] - 1)) * sizeof(float);
        if (ws_size >= need) { C = cands[i]; break; }
    }
    int T = Ll / C;
    float* P_ws = extra;
    float* Q_ws = P_ws + BMD * C;
    float* S_ws = Q_ws + BMD * C;

    kern_wea <<<Bb * Ll / 32, 256, 0, stream>>>(skills, responses, k_emb, v_emb, Mk,
                                                e_W, e_b, a_W, a_b, w_ws, e_ws, a_ws);
    if (C > 1) {
        kern_scan_pq<<<Bb * C, 128, 0, stream>>>(w_ws, e_ws, a_ws, P_ws, Q_ws, C, T);
        int cgrid = (int)(BMD / 256);
        if      (C == 8) kern_scan_comb_t<8><<<cgrid, 256, 0, stream>>>(Mv0, P_ws, Q_ws, S_ws);
        else if (C == 5) kern_scan_comb_t<5><<<cgrid, 256, 0, stream>>>(Mv0, P_ws, Q_ws, S_ws);
        else             kern_scan_comb_t<2><<<cgrid, 256, 0, stream>>>(Mv0, P_ws, Q_ws, S_ws);
    }
    kern_scan_rd<<<Bb * C, 128, 0, stream>>>(Mv0, S_ws, w_ws, e_ws, a_ws, read_ws, C, T);
    kern_out<<<Bb * (Ll - 1) / 32, 256, 0, stream>>>(skills, read_ws, k_emb, f_W, f_b, p_W, p_b, out);
}